// Round 1
// baseline (1238.521 us; speedup 1.0000x reference)
//
#include <hip/hip_runtime.h>
#include <hip/hip_bf16.h>
#include <math.h>

namespace {
constexpr int kB = 2;
constexpr int kL = 2048;
constexpr int kD = 1024;
constexpr int kH = 16;
constexpr int kHD = 64;
constexpr float kScale = 0.125f;    // HD^-0.5
constexpr float kRecency = 0.1f;
constexpr float kEps = 1e-8f;

// workspace layout (in floats)
constexpr size_t kQOff = 0;
constexpr size_t kKOff = kQOff + (size_t)kB * kH * kL * kHD;   // 4194304
constexpr size_t kMOff = kKOff + (size_t)kB * kH * kL * kHD;   // 8388608
constexpr size_t kIlOff = kMOff + (size_t)kB * kH * kL;        // +65536
constexpr size_t kRsOff = kIlOff + (size_t)kB * kH * kL;       // +65536
}  // namespace

// ---------------------------------------------------------------------------
// K1: q/k projection.  C[m][n] = dot(x[m,:], W[n,:]) + bias[n], n in [0,2048)
// scattered into q[b][h][l][hd], k[b][h][l][hd].
// ---------------------------------------------------------------------------
__global__ __launch_bounds__(256) void k_qkproj(const float* __restrict__ x,
                                                const float* __restrict__ w,
                                                const float* __restrict__ bias,
                                                float* __restrict__ qo,
                                                float* __restrict__ ko) {
  __shared__ float As[16][68];  // [kk][m]
  __shared__ float Bs[16][68];  // [kk][n]
  const int tid = threadIdx.x;
  const int m0 = blockIdx.x * 64;
  const int n0 = blockIdx.y * 64;
  const int tx = tid & 15, ty = tid >> 4;
  const int lr = tid >> 2;
  const int lc = (tid & 3) * 4;
  float acc[4][4] = {};
  for (int k0 = 0; k0 < kD; k0 += 16) {
    const float4 av = *reinterpret_cast<const float4*>(x + (size_t)(m0 + lr) * kD + k0 + lc);
    const float4 bv = *reinterpret_cast<const float4*>(w + (size_t)(n0 + lr) * kD + k0 + lc);
    As[lc + 0][lr] = av.x; As[lc + 1][lr] = av.y; As[lc + 2][lr] = av.z; As[lc + 3][lr] = av.w;
    Bs[lc + 0][lr] = bv.x; Bs[lc + 1][lr] = bv.y; Bs[lc + 2][lr] = bv.z; Bs[lc + 3][lr] = bv.w;
    __syncthreads();
#pragma unroll
    for (int kk = 0; kk < 16; ++kk) {
      const float4 a4 = *reinterpret_cast<const float4*>(&As[kk][ty * 4]);
      const float4 b4 = *reinterpret_cast<const float4*>(&Bs[kk][tx * 4]);
      const float a[4] = {a4.x, a4.y, a4.z, a4.w};
      const float b[4] = {b4.x, b4.y, b4.z, b4.w};
#pragma unroll
      for (int i = 0; i < 4; ++i)
#pragma unroll
        for (int j = 0; j < 4; ++j) acc[i][j] = fmaf(a[i], b[j], acc[i][j]);
    }
    __syncthreads();
  }
#pragma unroll
  for (int i = 0; i < 4; ++i) {
    const int m = m0 + ty * 4 + i;
    const int bb = m >> 11;         // m / L
    const int ll = m & (kL - 1);
#pragma unroll
    for (int j = 0; j < 4; ++j) {
      const int n = n0 + tx * 4 + j;
      const float v = acc[i][j] + bias[n];
      float* dst = (n < kD) ? qo : ko;
      const int nn = n & (kD - 1);
      const int h = nn >> 6, hd = nn & 63;
      dst[(((size_t)bb * kH + h) * kL + ll) * kHD + hd] = v;
    }
  }
}

// ---------------------------------------------------------------------------
// K2: per-(b,h,row) softmax stats: m = max_k s, il = 1/sum exp(s-m).
// block = (q-tile of 32 rows) x (bh).  thread owns 4 q rows x 4 k cols.
// ---------------------------------------------------------------------------
__global__ __launch_bounds__(256) void k_stats(const float* __restrict__ q,
                                               const float* __restrict__ k,
                                               float* __restrict__ mo,
                                               float* __restrict__ ilo) {
  __shared__ float qs[32][68];
  __shared__ float ks[128][68];
  const int tid = threadIdx.x;
  const int qt = blockIdx.x;  // 0..63
  const int bh = blockIdx.y;  // 0..31
  const float* qb = q + ((size_t)bh * kL + qt * 32) * kHD;
  const float* kb = k + (size_t)bh * kL * kHD;
#pragma unroll
  for (int c = 0; c < 2; ++c) {
    const int idx = (tid + c * 256) * 4;
    const int r = idx >> 6, cc = idx & 63;
    *reinterpret_cast<float4*>(&qs[r][cc]) =
        *reinterpret_cast<const float4*>(qb + (size_t)r * kHD + cc);
  }
  const int qg = tid >> 5;  // 0..7
  const int kg = tid & 31;  // 0..31
  float mr[4], lr[4];
#pragma unroll
  for (int i = 0; i < 4; ++i) { mr[i] = -INFINITY; lr[i] = 0.f; }
  for (int kt = 0; kt < kL; kt += 128) {
    __syncthreads();
#pragma unroll
    for (int c = 0; c < 8; ++c) {
      const int idx = (tid + c * 256) * 4;
      const int r = idx >> 6, cc = idx & 63;
      *reinterpret_cast<float4*>(&ks[r][cc]) =
          *reinterpret_cast<const float4*>(kb + (size_t)(kt + r) * kHD + cc);
    }
    __syncthreads();
    float s[4][4] = {};
#pragma unroll
    for (int d = 0; d < kHD; d += 4) {
      float4 q4[4], k4[4];
#pragma unroll
      for (int i = 0; i < 4; ++i) q4[i] = *reinterpret_cast<const float4*>(&qs[qg * 4 + i][d]);
#pragma unroll
      for (int j = 0; j < 4; ++j) k4[j] = *reinterpret_cast<const float4*>(&ks[kg * 4 + j][d]);
#pragma unroll
      for (int i = 0; i < 4; ++i)
#pragma unroll
        for (int j = 0; j < 4; ++j) {
          s[i][j] = fmaf(q4[i].x, k4[j].x, s[i][j]);
          s[i][j] = fmaf(q4[i].y, k4[j].y, s[i][j]);
          s[i][j] = fmaf(q4[i].z, k4[j].z, s[i][j]);
          s[i][j] = fmaf(q4[i].w, k4[j].w, s[i][j]);
        }
    }
#pragma unroll
    for (int i = 0; i < 4; ++i) {
      float sc[4];
#pragma unroll
      for (int j = 0; j < 4; ++j) sc[j] = s[i][j] * kScale;
      const float tm = fmaxf(fmaxf(sc[0], sc[1]), fmaxf(sc[2], sc[3]));
      if (tm > mr[i]) {
        lr[i] *= __expf(mr[i] - tm);  // exp(-inf)=0 on first tile: lr stays 0
        mr[i] = tm;
      }
#pragma unroll
      for (int j = 0; j < 4; ++j) lr[i] += __expf(sc[j] - mr[i]);
    }
  }
#pragma unroll
  for (int i = 0; i < 4; ++i) {
    for (int off = 16; off > 0; off >>= 1) {
      const float mo2 = __shfl_xor(mr[i], off);
      const float lo2 = __shfl_xor(lr[i], off);
      const float mn = fmaxf(mr[i], mo2);
      lr[i] = lr[i] * __expf(mr[i] - mn) + lo2 * __expf(mo2 - mn);
      mr[i] = mn;
    }
  }
  if (kg == 0) {
#pragma unroll
    for (int i = 0; i < 4; ++i) {
      const size_t idx = (size_t)bh * kL + qt * 32 + qg * 4 + i;
      mo[idx] = mr[i];
      ilo[idx] = 1.0f / lr[i];
    }
  }
}

// ---------------------------------------------------------------------------
// K3: recompute scores per head, accumulate head-mean softmax weight,
// apply temporal decay, write unnormalized attn to d_out, accumulate rowsum.
// ---------------------------------------------------------------------------
__global__ __launch_bounds__(256) void k_attn(const float* __restrict__ q,
                                              const float* __restrict__ k,
                                              const float* __restrict__ ms,
                                              const float* __restrict__ ils,
                                              const float* __restrict__ td,
                                              float* __restrict__ attn,
                                              float* __restrict__ rowsum) {
  __shared__ float qs[32][68];
  __shared__ float ks[128][68];
  __shared__ float m_s[32], il_s[32];
  const int tid = threadIdx.x;
  const int ktile = blockIdx.x;  // 0..15
  const int qtile = blockIdx.y;  // 0..63
  const int b = blockIdx.z;      // 0..1
  const int qg = tid >> 5, kg = tid & 31;
  float wacc[4][4] = {};
  for (int h = 0; h < kH; ++h) {
    __syncthreads();
    const size_t bh = (size_t)b * kH + h;
    const float* qb = q + (bh * kL + qtile * 32) * kHD;
    const float* kb = k + (bh * kL + ktile * 128) * kHD;
#pragma unroll
    for (int c = 0; c < 2; ++c) {
      const int idx = (tid + c * 256) * 4;
      const int r = idx >> 6, cc = idx & 63;
      *reinterpret_cast<float4*>(&qs[r][cc]) =
          *reinterpret_cast<const float4*>(qb + (size_t)r * kHD + cc);
    }
#pragma unroll
    for (int c = 0; c < 8; ++c) {
      const int idx = (tid + c * 256) * 4;
      const int r = idx >> 6, cc = idx & 63;
      *reinterpret_cast<float4*>(&ks[r][cc]) =
          *reinterpret_cast<const float4*>(kb + (size_t)r * kHD + cc);
    }
    if (tid < 32) {
      m_s[tid] = ms[bh * kL + qtile * 32 + tid];
      il_s[tid] = ils[bh * kL + qtile * 32 + tid];
    }
    __syncthreads();
    float s[4][4] = {};
#pragma unroll
    for (int d = 0; d < kHD; d += 4) {
      float4 q4[4], k4[4];
#pragma unroll
      for (int i = 0; i < 4; ++i) q4[i] = *reinterpret_cast<const float4*>(&qs[qg * 4 + i][d]);
#pragma unroll
      for (int j = 0; j < 4; ++j) k4[j] = *reinterpret_cast<const float4*>(&ks[kg * 4 + j][d]);
#pragma unroll
      for (int i = 0; i < 4; ++i)
#pragma unroll
        for (int j = 0; j < 4; ++j) {
          s[i][j] = fmaf(q4[i].x, k4[j].x, s[i][j]);
          s[i][j] = fmaf(q4[i].y, k4[j].y, s[i][j]);
          s[i][j] = fmaf(q4[i].z, k4[j].z, s[i][j]);
          s[i][j] = fmaf(q4[i].w, k4[j].w, s[i][j]);
        }
    }
#pragma unroll
    for (int i = 0; i < 4; ++i) {
      const float mi = m_s[qg * 4 + i];
      const float ili = il_s[qg * 4 + i];
#pragma unroll
      for (int j = 0; j < 4; ++j)
        wacc[i][j] = fmaf(__expf(s[i][j] * kScale - mi), ili, wacc[i][j]);
    }
  }
  const float invH = 1.0f / kH;
#pragma unroll
  for (int i = 0; i < 4; ++i) {
    const int row = qtile * 32 + qg * 4 + i;
    const size_t base = ((size_t)b * kL + row) * kL + ktile * 128 + kg * 4;
    const float4 t4 = *reinterpret_cast<const float4*>(td + base);
    float4 o;
    o.x = wacc[i][0] * invH * __expf(-kRecency * t4.x);
    o.y = wacc[i][1] * invH * __expf(-kRecency * t4.y);
    o.z = wacc[i][2] * invH * __expf(-kRecency * t4.z);
    o.w = wacc[i][3] * invH * __expf(-kRecency * t4.w);
    *reinterpret_cast<float4*>(attn + base) = o;
    float rs = o.x + o.y + o.z + o.w;
#pragma unroll
    for (int off = 16; off > 0; off >>= 1) rs += __shfl_xor(rs, off);
    if (kg == 0) atomicAdd(&rowsum[(size_t)b * kL + row], rs);
  }
}

// ---------------------------------------------------------------------------
// K4a: in-place row renormalization of attn weights.
// ---------------------------------------------------------------------------
__global__ __launch_bounds__(256) void k_norm(float* __restrict__ attn,
                                              const float* __restrict__ rowsum) {
  const int row = blockIdx.x;  // 0..B*L-1
  const float inv = 1.0f / (rowsum[row] + kEps);
  float* p = attn + (size_t)row * kL;
  const int tid = threadIdx.x;
#pragma unroll
  for (int c = 0; c < 2; ++c) {
    const int idx = (tid + c * 256) * 4;
    float4 v = *reinterpret_cast<float4*>(p + idx);
    v.x *= inv; v.y *= inv; v.z *= inv; v.w *= inv;
    *reinterpret_cast<float4*>(p + idx) = v;
  }
}

// ---------------------------------------------------------------------------
// K4b: output GEMM  out[b,q,:] = attn[b,q,:] @ x[b,:,:]
// ---------------------------------------------------------------------------
__global__ __launch_bounds__(256) void k_out(const float* __restrict__ attn,
                                             const float* __restrict__ x,
                                             float* __restrict__ out) {
  __shared__ float As[16][68];  // [kk][m]
  __shared__ float Bs[16][68];  // [kk][n]
  const int tid = threadIdx.x;
  const int m0 = blockIdx.x * 64;  // q rows
  const int n0 = blockIdx.y * 64;  // d cols
  const int b = blockIdx.z;
  const float* A = attn + (size_t)b * kL * kL;
  const float* X = x + (size_t)b * kL * kD;
  const int tx = tid & 15, ty = tid >> 4;
  const int alr = tid >> 2;
  const int alc = (tid & 3) * 4;
  const int brr = tid >> 4;
  const int bcc = (tid & 15) * 4;
  float acc[4][4] = {};
  for (int k0 = 0; k0 < kL; k0 += 16) {
    const float4 av = *reinterpret_cast<const float4*>(A + (size_t)(m0 + alr) * kL + k0 + alc);
    As[alc + 0][alr] = av.x; As[alc + 1][alr] = av.y; As[alc + 2][alr] = av.z; As[alc + 3][alr] = av.w;
    *reinterpret_cast<float4*>(&Bs[brr][bcc]) =
        *reinterpret_cast<const float4*>(X + (size_t)(k0 + brr) * kD + n0 + bcc);
    __syncthreads();
#pragma unroll
    for (int kk = 0; kk < 16; ++kk) {
      const float4 a4 = *reinterpret_cast<const float4*>(&As[kk][ty * 4]);
      const float4 b4 = *reinterpret_cast<const float4*>(&Bs[kk][tx * 4]);
      const float a[4] = {a4.x, a4.y, a4.z, a4.w};
      const float bb[4] = {b4.x, b4.y, b4.z, b4.w};
#pragma unroll
      for (int i = 0; i < 4; ++i)
#pragma unroll
        for (int j = 0; j < 4; ++j) acc[i][j] = fmaf(a[i], bb[j], acc[i][j]);
    }
    __syncthreads();
  }
#pragma unroll
  for (int i = 0; i < 4; ++i) {
    const int m = m0 + ty * 4 + i;
    float4 o;
    o.x = acc[i][0]; o.y = acc[i][1]; o.z = acc[i][2]; o.w = acc[i][3];
    *reinterpret_cast<float4*>(out + ((size_t)b * kL + m) * kD + n0 + tx * 4) = o;
  }
}

extern "C" void kernel_launch(void* const* d_in, const int* in_sizes, int n_in,
                              void* d_out, int out_size, void* d_ws, size_t ws_size,
                              hipStream_t stream) {
  (void)in_sizes; (void)n_in; (void)out_size; (void)ws_size;
  const float* x = (const float*)d_in[0];
  const float* td = (const float*)d_in[1];
  const float* w = (const float*)d_in[2];
  const float* bias = (const float*)d_in[3];
  float* out = (float*)d_out;                        // [B,L,D]
  float* attn = out + (size_t)kB * kL * kD;          // [B,L,L]
  float* ws = (float*)d_ws;
  float* qb = ws + kQOff;
  float* kb = ws + kKOff;
  float* mb = ws + kMOff;
  float* ilb = ws + kIlOff;
  float* rsb = ws + kRsOff;

  hipLaunchKernelGGL(k_qkproj, dim3(64, 32), dim3(256), 0, stream, x, w, bias, qb, kb);
  hipLaunchKernelGGL(k_stats, dim3(64, 32), dim3(256), 0, stream, qb, kb, mb, ilb);
  hipMemsetAsync(rsb, 0, (size_t)kB * kL * sizeof(float), stream);
  hipLaunchKernelGGL(k_attn, dim3(16, 64, 2), dim3(256), 0, stream, qb, kb, mb, ilb, td, attn, rsb);
  hipLaunchKernelGGL(k_norm, dim3(kB * kL), dim3(256), 0, stream, attn, rsb);
  hipLaunchKernelGGL(k_out, dim3(32, 16, 2), dim3(256), 0, stream, attn, x, out);
}

// Round 2
// 792.515 us; speedup vs baseline: 1.5628x; 1.5628x over previous
//
#include <hip/hip_runtime.h>
#include <hip/hip_bf16.h>
#include <math.h>

namespace {
constexpr int kB = 2;
constexpr int kL = 2048;
constexpr int kD = 1024;
constexpr int kH = 16;
constexpr int kHD = 64;
constexpr float kScale = 0.125f;    // HD^-0.5
constexpr float kRecency = 0.1f;
constexpr float kEps = 1e-8f;

constexpr size_t kQKElems = (size_t)kB * kH * kL * kHD;  // 4194304 per array
}  // namespace

typedef __bf16 bf16x8 __attribute__((ext_vector_type(8)));
typedef float f32x4 __attribute__((ext_vector_type(4)));
typedef unsigned short u16;
typedef u16 u16x8 __attribute__((ext_vector_type(8)));

__device__ inline u16 f2bf(float v) {
  unsigned int u = __float_as_uint(v);
  unsigned int r = (u + 0x7FFFu + ((u >> 16) & 1u)) >> 16;
  return (u16)r;
}
__device__ inline float bf2f(u16 u) { return __uint_as_float((unsigned int)u << 16); }

// ---------------------------------------------------------------------------
// K1: q/k projection (fp32 VALU GEMM), epilogue splits to bf16 hi/lo arrays
// laid out [b][h][l][hd].
// ---------------------------------------------------------------------------
__global__ __launch_bounds__(256) void k_qkproj(const float* __restrict__ x,
                                                const float* __restrict__ w,
                                                const float* __restrict__ bias,
                                                u16* __restrict__ qhi, u16* __restrict__ qlo,
                                                u16* __restrict__ khi, u16* __restrict__ klo) {
  __shared__ float As[16][68];  // [kk][m]
  __shared__ float Bs[16][68];  // [kk][n]
  const int tid = threadIdx.x;
  const int m0 = blockIdx.x * 64;
  const int n0 = blockIdx.y * 64;
  const int tx = tid & 15, ty = tid >> 4;
  const int lr = tid >> 2;
  const int lc = (tid & 3) * 4;
  float acc[4][4] = {};
  for (int k0 = 0; k0 < kD; k0 += 16) {
    const float4 av = *reinterpret_cast<const float4*>(x + (size_t)(m0 + lr) * kD + k0 + lc);
    const float4 bv = *reinterpret_cast<const float4*>(w + (size_t)(n0 + lr) * kD + k0 + lc);
    As[lc + 0][lr] = av.x; As[lc + 1][lr] = av.y; As[lc + 2][lr] = av.z; As[lc + 3][lr] = av.w;
    Bs[lc + 0][lr] = bv.x; Bs[lc + 1][lr] = bv.y; Bs[lc + 2][lr] = bv.z; Bs[lc + 3][lr] = bv.w;
    __syncthreads();
#pragma unroll
    for (int kk = 0; kk < 16; ++kk) {
      const float4 a4 = *reinterpret_cast<const float4*>(&As[kk][ty * 4]);
      const float4 b4 = *reinterpret_cast<const float4*>(&Bs[kk][tx * 4]);
      const float a[4] = {a4.x, a4.y, a4.z, a4.w};
      const float b[4] = {b4.x, b4.y, b4.z, b4.w};
#pragma unroll
      for (int i = 0; i < 4; ++i)
#pragma unroll
        for (int j = 0; j < 4; ++j) acc[i][j] = fmaf(a[i], b[j], acc[i][j]);
    }
    __syncthreads();
  }
  const int n_ = n0 + tx * 4;
  const bool isq = (n_ < kD);
  const int nn = n_ & (kD - 1);
  const int h = nn >> 6, hd = nn & 63;
  u16* __restrict__ dh = isq ? qhi : khi;
  u16* __restrict__ dl = isq ? qlo : klo;
#pragma unroll
  for (int i = 0; i < 4; ++i) {
    const int m = m0 + ty * 4 + i;
    const int bb = m >> 11;
    const int ll = m & (kL - 1);
    ushort4 h4, l4;
#pragma unroll
    for (int j = 0; j < 4; ++j) {
      const float v = acc[i][j] + bias[n_ + j];
      const u16 hu = f2bf(v);
      const u16 lu = f2bf(v - bf2f(hu));
      ((u16*)&h4)[j] = hu;
      ((u16*)&l4)[j] = lu;
    }
    const size_t idx = (((size_t)bb * kH + h) * kL + ll) * kHD + hd;
    *reinterpret_cast<ushort4*>(dh + idx) = h4;
    *reinterpret_cast<ushort4*>(dl + idx) = l4;
  }
}

// ---------------------------------------------------------------------------
// K2: softmax stats via MFMA (hi/lo split). Block = 64 q-rows of one bh,
// 4 waves (16 rows each). K staged 64 cols/iter in frag-order LDS.
// ---------------------------------------------------------------------------
__global__ __launch_bounds__(256) void k_stats(const u16* __restrict__ qh, const u16* __restrict__ ql,
                                               const u16* __restrict__ kh, const u16* __restrict__ kl,
                                               float* __restrict__ mo, float* __restrict__ ilo) {
  __shared__ u16 Kh[4096];  // 64 cols x 64 hd, frag layout
  __shared__ u16 Kl[4096];
  const int tid = threadIdx.x;
  const int wave = tid >> 6, lane = tid & 63;
  const int qt = blockIdx.x;   // 0..31 (64-row blocks)
  const int bh = blockIdx.y;   // 0..31
  const size_t base = (size_t)bh * kL * kHD;
  const int row0 = qt * 64 + wave * 16;
  const size_t qoff = base + (size_t)(row0 + (lane & 15)) * kHD + (lane >> 4) * 8;
  const bf16x8 aqh0 = *reinterpret_cast<const bf16x8*>(qh + qoff);
  const bf16x8 aqh1 = *reinterpret_cast<const bf16x8*>(qh + qoff + 32);
  const bf16x8 aql0 = *reinterpret_cast<const bf16x8*>(ql + qoff);
  const bf16x8 aql1 = *reinterpret_cast<const bf16x8*>(ql + qoff + 32);
  float m[4], l[4];
#pragma unroll
  for (int r = 0; r < 4; ++r) { m[r] = -INFINITY; l[r] = 0.f; }
  for (int kt = 0; kt < kL; kt += 64) {
    __syncthreads();
#pragma unroll
    for (int c = tid; c < 512; c += 256) {
      const int col = c >> 3, cc = c & 7;
      const size_t g = base + (size_t)(kt + col) * kHD + cc * 8;
      const int lo = ((((col >> 4) * 2 + (cc >> 2)) * 4 + (cc & 3)) * 16 + (col & 15)) * 8;
      *reinterpret_cast<u16x8*>(&Kh[lo]) = *reinterpret_cast<const u16x8*>(kh + g);
      *reinterpret_cast<u16x8*>(&Kl[lo]) = *reinterpret_cast<const u16x8*>(kl + g);
    }
    __syncthreads();
#pragma unroll
    for (int cs = 0; cs < 4; ++cs) {
      const int f0 = (((cs * 2 + 0) * 4 + (lane >> 4)) * 16 + (lane & 15)) * 8;
      const int f1 = (((cs * 2 + 1) * 4 + (lane >> 4)) * 16 + (lane & 15)) * 8;
      const bf16x8 bh0 = *reinterpret_cast<const bf16x8*>(&Kh[f0]);
      const bf16x8 bh1 = *reinterpret_cast<const bf16x8*>(&Kh[f1]);
      const bf16x8 bl0 = *reinterpret_cast<const bf16x8*>(&Kl[f0]);
      const bf16x8 bl1 = *reinterpret_cast<const bf16x8*>(&Kl[f1]);
      f32x4 s = {0.f, 0.f, 0.f, 0.f};
      s = __builtin_amdgcn_mfma_f32_16x16x32_bf16(aqh0, bh0, s, 0, 0, 0);
      s = __builtin_amdgcn_mfma_f32_16x16x32_bf16(aqh1, bh1, s, 0, 0, 0);
      s = __builtin_amdgcn_mfma_f32_16x16x32_bf16(aqh0, bl0, s, 0, 0, 0);
      s = __builtin_amdgcn_mfma_f32_16x16x32_bf16(aqh1, bl1, s, 0, 0, 0);
      s = __builtin_amdgcn_mfma_f32_16x16x32_bf16(aql0, bh0, s, 0, 0, 0);
      s = __builtin_amdgcn_mfma_f32_16x16x32_bf16(aql1, bh1, s, 0, 0, 0);
#pragma unroll
      for (int r = 0; r < 4; ++r) {
        const float sc = s[r] * kScale;
        const float nm = fmaxf(m[r], sc);
        l[r] = l[r] * __expf(m[r] - nm) + __expf(sc - nm);
        m[r] = nm;
      }
    }
  }
  // merge across the 16 lanes of each lane-group (cols)
#pragma unroll
  for (int r = 0; r < 4; ++r) {
#pragma unroll
    for (int off = 1; off < 16; off <<= 1) {
      const float mo2 = __shfl_xor(m[r], off);
      const float lo2 = __shfl_xor(l[r], off);
      const float nm = fmaxf(m[r], mo2);
      l[r] = l[r] * __expf(m[r] - nm) + lo2 * __expf(mo2 - nm);
      m[r] = nm;
    }
  }
  if ((lane & 15) == 0) {
#pragma unroll
    for (int r = 0; r < 4; ++r) {
      const int row = row0 + (lane >> 4) * 4 + r;
      mo[(size_t)bh * kL + row] = m[r];
      ilo[(size_t)bh * kL + row] = 1.0f / l[r];
    }
  }
}

// ---------------------------------------------------------------------------
// K3: head-mean weights via MFMA. Block = 64 q-rows x 128 k-cols, loops heads;
// K staged per head in frag-order LDS, Q frags direct from global.
// ---------------------------------------------------------------------------
__global__ __launch_bounds__(256) void k_attn(const u16* __restrict__ qh, const u16* __restrict__ ql,
                                              const u16* __restrict__ kh, const u16* __restrict__ kl,
                                              const float* __restrict__ ms, const float* __restrict__ ils,
                                              const float* __restrict__ td,
                                              float* __restrict__ attn, float* __restrict__ rowsum) {
  __shared__ u16 Kh[8192];  // 128 cols x 64 hd, frag layout
  __shared__ u16 Kl[8192];
  __shared__ float msS[16][64];
  __shared__ float ilS[16][64];
  const int tid = threadIdx.x;
  const int wave = tid >> 6, lane = tid & 63;
  const int kb = blockIdx.x;  // 0..15 (128 cols)
  const int qb = blockIdx.y;  // 0..31 (64 rows)
  const int b = blockIdx.z;
#pragma unroll
  for (int c = tid; c < 1024; c += 256) {
    const int h = c >> 6, r = c & 63;
    msS[h][r] = ms[((size_t)b * kH + h) * kL + qb * 64 + r];
    ilS[h][r] = ils[((size_t)b * kH + h) * kL + qb * 64 + r];
  }
  const int row0 = qb * 64 + wave * 16;
  float wacc[8][4] = {};
  for (int h = 0; h < kH; ++h) {
    const size_t base = ((size_t)b * kH + h) * kL * kHD;
    __syncthreads();
#pragma unroll
    for (int c = tid; c < 1024; c += 256) {
      const int col = c >> 3, cc = c & 7;
      const size_t g = base + (size_t)(kb * 128 + col) * kHD + cc * 8;
      const int lo = ((((col >> 4) * 2 + (cc >> 2)) * 4 + (cc & 3)) * 16 + (col & 15)) * 8;
      *reinterpret_cast<u16x8*>(&Kh[lo]) = *reinterpret_cast<const u16x8*>(kh + g);
      *reinterpret_cast<u16x8*>(&Kl[lo]) = *reinterpret_cast<const u16x8*>(kl + g);
    }
    __syncthreads();
    const size_t qoff = base + (size_t)(row0 + (lane & 15)) * kHD + (lane >> 4) * 8;
    const bf16x8 aqh0 = *reinterpret_cast<const bf16x8*>(qh + qoff);
    const bf16x8 aqh1 = *reinterpret_cast<const bf16x8*>(qh + qoff + 32);
    const bf16x8 aql0 = *reinterpret_cast<const bf16x8*>(ql + qoff);
    const bf16x8 aql1 = *reinterpret_cast<const bf16x8*>(ql + qoff + 32);
    const f32x4 mrow = *reinterpret_cast<const f32x4*>(&msS[h][wave * 16 + (lane >> 4) * 4]);
    const f32x4 irow = *reinterpret_cast<const f32x4*>(&ilS[h][wave * 16 + (lane >> 4) * 4]);
#pragma unroll
    for (int cs = 0; cs < 8; ++cs) {
      const int f0 = (((cs * 2 + 0) * 4 + (lane >> 4)) * 16 + (lane & 15)) * 8;
      const int f1 = (((cs * 2 + 1) * 4 + (lane >> 4)) * 16 + (lane & 15)) * 8;
      const bf16x8 bkh0 = *reinterpret_cast<const bf16x8*>(&Kh[f0]);
      const bf16x8 bkh1 = *reinterpret_cast<const bf16x8*>(&Kh[f1]);
      const bf16x8 bkl0 = *reinterpret_cast<const bf16x8*>(&Kl[f0]);
      const bf16x8 bkl1 = *reinterpret_cast<const bf16x8*>(&Kl[f1]);
      f32x4 s = {0.f, 0.f, 0.f, 0.f};
      s = __builtin_amdgcn_mfma_f32_16x16x32_bf16(aqh0, bkh0, s, 0, 0, 0);
      s = __builtin_amdgcn_mfma_f32_16x16x32_bf16(aqh1, bkh1, s, 0, 0, 0);
      s = __builtin_amdgcn_mfma_f32_16x16x32_bf16(aqh0, bkl0, s, 0, 0, 0);
      s = __builtin_amdgcn_mfma_f32_16x16x32_bf16(aqh1, bkl1, s, 0, 0, 0);
      s = __builtin_amdgcn_mfma_f32_16x16x32_bf16(aql0, bkh0, s, 0, 0, 0);
      s = __builtin_amdgcn_mfma_f32_16x16x32_bf16(aql1, bkh1, s, 0, 0, 0);
#pragma unroll
      for (int r = 0; r < 4; ++r)
        wacc[cs][r] += __expf(fmaf(s[r], kScale, -mrow[r])) * irow[r];
    }
  }
  const float invH = 1.0f / kH;
#pragma unroll
  for (int r = 0; r < 4; ++r) {
    const int row = row0 + (lane >> 4) * 4 + r;
    float rs = 0.f;
#pragma unroll
    for (int cs = 0; cs < 8; ++cs) {
      const int col = kb * 128 + cs * 16 + (lane & 15);
      const size_t idx = ((size_t)b * kL + row) * kL + col;
      const float o = wacc[cs][r] * invH * __expf(-kRecency * td[idx]);
      attn[idx] = o;
      rs += o;
    }
#pragma unroll
    for (int off = 1; off < 16; off <<= 1) rs += __shfl_xor(rs, off);
    if ((lane & 15) == 0) atomicAdd(&rowsum[(size_t)b * kL + row], rs);
  }
}

// ---------------------------------------------------------------------------
// K4a: in-place row renormalization of attn weights.
// ---------------------------------------------------------------------------
__global__ __launch_bounds__(256) void k_norm(float* __restrict__ attn,
                                              const float* __restrict__ rowsum) {
  const int row = blockIdx.x;
  const float inv = 1.0f / (rowsum[row] + kEps);
  float* p = attn + (size_t)row * kL;
  const int tid = threadIdx.x;
#pragma unroll
  for (int c = 0; c < 2; ++c) {
    const int idx = (tid + c * 256) * 4;
    float4 v = *reinterpret_cast<float4*>(p + idx);
    v.x *= inv; v.y *= inv; v.z *= inv; v.w *= inv;
    *reinterpret_cast<float4*>(p + idx) = v;
  }
}

// ---------------------------------------------------------------------------
// K4b: output GEMM  out[b,q,:] = attn[b,q,:] @ x[b,:,:]   (fp32 VALU)
// ---------------------------------------------------------------------------
__global__ __launch_bounds__(256) void k_out(const float* __restrict__ attn,
                                             const float* __restrict__ x,
                                             float* __restrict__ out) {
  __shared__ float As[16][68];
  __shared__ float Bs[16][68];
  const int tid = threadIdx.x;
  const int m0 = blockIdx.x * 64;
  const int n0 = blockIdx.y * 64;
  const int b = blockIdx.z;
  const float* A = attn + (size_t)b * kL * kL;
  const float* X = x + (size_t)b * kL * kD;
  const int tx = tid & 15, ty = tid >> 4;
  const int alr = tid >> 2;
  const int alc = (tid & 3) * 4;
  const int brr = tid >> 4;
  const int bcc = (tid & 15) * 4;
  float acc[4][4] = {};
  for (int k0 = 0; k0 < kL; k0 += 16) {
    const float4 av = *reinterpret_cast<const float4*>(A + (size_t)(m0 + alr) * kL + k0 + alc);
    As[alc + 0][alr] = av.x; As[alc + 1][alr] = av.y; As[alc + 2][alr] = av.z; As[alc + 3][alr] = av.w;
    *reinterpret_cast<float4*>(&Bs[brr][bcc]) =
        *reinterpret_cast<const float4*>(X + (size_t)(k0 + brr) * kD + n0 + bcc);
    __syncthreads();
#pragma unroll
    for (int kk = 0; kk < 16; ++kk) {
      const float4 a4 = *reinterpret_cast<const float4*>(&As[kk][ty * 4]);
      const float4 b4 = *reinterpret_cast<const float4*>(&Bs[kk][tx * 4]);
      const float a[4] = {a4.x, a4.y, a4.z, a4.w};
      const float bb[4] = {b4.x, b4.y, b4.z, b4.w};
#pragma unroll
      for (int i = 0; i < 4; ++i)
#pragma unroll
        for (int j = 0; j < 4; ++j) acc[i][j] = fmaf(a[i], bb[j], acc[i][j]);
    }
    __syncthreads();
  }
#pragma unroll
  for (int i = 0; i < 4; ++i) {
    const int m = m0 + ty * 4 + i;
    float4 o;
    o.x = acc[i][0]; o.y = acc[i][1]; o.z = acc[i][2]; o.w = acc[i][3];
    *reinterpret_cast<float4*>(out + ((size_t)b * kL + m) * kD + n0 + tx * 4) = o;
  }
}

extern "C" void kernel_launch(void* const* d_in, const int* in_sizes, int n_in,
                              void* d_out, int out_size, void* d_ws, size_t ws_size,
                              hipStream_t stream) {
  (void)in_sizes; (void)n_in; (void)out_size; (void)ws_size;
  const float* x = (const float*)d_in[0];
  const float* td = (const float*)d_in[1];
  const float* w = (const float*)d_in[2];
  const float* bias = (const float*)d_in[3];
  float* out = (float*)d_out;                        // [B,L,D]
  float* attn = out + (size_t)kB * kL * kD;          // [B,L,L]

  u16* qhi = (u16*)d_ws;
  u16* qlo = qhi + kQKElems;
  u16* khi = qlo + kQKElems;
  u16* klo = khi + kQKElems;
  float* mb = (float*)(klo + kQKElems);
  float* ilb = mb + (size_t)kB * kH * kL;
  float* rsb = ilb + (size_t)kB * kH * kL;

  hipLaunchKernelGGL(k_qkproj, dim3(64, 32), dim3(256), 0, stream, x, w, bias, qhi, qlo, khi, klo);
  hipLaunchKernelGGL(k_stats, dim3(32, 32), dim3(256), 0, stream, qhi, qlo, khi, klo, mb, ilb);
  hipMemsetAsync(rsb, 0, (size_t)kB * kL * sizeof(float), stream);
  hipLaunchKernelGGL(k_attn, dim3(16, 32, 2), dim3(256), 0, stream, qhi, qlo, khi, klo, mb, ilb, td, attn, rsb);
  hipLaunchKernelGGL(k_norm, dim3(kB * kL), dim3(256), 0, stream, attn, rsb);
  hipLaunchKernelGGL(k_out, dim3(32, 16, 2), dim3(256), 0, stream, attn, x, out);
}

// Round 4
// 507.076 us; speedup vs baseline: 2.4425x; 1.5629x over previous
//
#include <hip/hip_runtime.h>
#include <hip/hip_bf16.h>
#include <math.h>

namespace {
constexpr int kB = 2;
constexpr int kL = 2048;
constexpr int kD = 1024;
constexpr int kH = 16;
constexpr int kHD = 64;
constexpr float kScale = 0.125f;    // HD^-0.5
constexpr float kRecency = 0.1f;
constexpr float kEps = 1e-8f;

constexpr size_t kN4 = 4194304;  // B*H*L*HD elements per q/k array
}  // namespace

typedef __bf16 bf16x8 __attribute__((ext_vector_type(8)));
typedef float f32x4 __attribute__((ext_vector_type(4)));
typedef unsigned short u16;
typedef u16 u16x8 __attribute__((ext_vector_type(8)));

__device__ inline u16 f2bf(float v) {
  unsigned int u = __float_as_uint(v);
  unsigned int r = (u + 0x7FFFu + ((u >> 16) & 1u)) >> 16;
  return (u16)r;
}
__device__ inline float bf2f(u16 u) { return __uint_as_float((unsigned int)u << 16); }

// ---------------------------------------------------------------------------
// K0: straight conversion of x (4.19M floats) and W[0:2048] (2.10M floats)
// to bf16 hi/lo arrays.
// ---------------------------------------------------------------------------
__global__ __launch_bounds__(256) void k_cvt_xw(const float* __restrict__ x,
                                                const float* __restrict__ w,
                                                u16* __restrict__ xh, u16* __restrict__ xl,
                                                u16* __restrict__ wh, u16* __restrict__ wl) {
  const size_t id = (size_t)blockIdx.x * 256 + threadIdx.x;  // float4 index
  const bool isx = id < 1048576;
  const float4 v = isx ? reinterpret_cast<const float4*>(x)[id]
                       : reinterpret_cast<const float4*>(w)[id - 1048576];
  const float vv[4] = {v.x, v.y, v.z, v.w};
  ushort4 h4, l4;
#pragma unroll
  for (int c = 0; c < 4; ++c) {
    const u16 hu = f2bf(vv[c]);
    ((u16*)&h4)[c] = hu;
    ((u16*)&l4)[c] = f2bf(vv[c] - bf2f(hu));
  }
  const size_t o = (isx ? id : id - 1048576) * 4;
  if (isx) {
    *reinterpret_cast<ushort4*>(xh + o) = h4;
    *reinterpret_cast<ushort4*>(xl + o) = l4;
  } else {
    *reinterpret_cast<ushort4*>(wh + o) = h4;
    *reinterpret_cast<ushort4*>(wl + o) = l4;
  }
}

// ---------------------------------------------------------------------------
// K1: q/k projection via MFMA (C^T orientation: A = W rows, B = x rows).
// 128(n) x 128(m) tile, 4 waves (2x2 of 64x64), K_STEP=64, 3-term hi/lo.
// Epilogue writes q/k bf16 hi/lo straight into [b][h][l][hd] layout.
// ---------------------------------------------------------------------------
__global__ __launch_bounds__(256, 2) void k_qkproj(const u16* __restrict__ xh, const u16* __restrict__ xl,
                                                   const u16* __restrict__ wh, const u16* __restrict__ wl,
                                                   const float* __restrict__ bias,
                                                   u16* __restrict__ qhi, u16* __restrict__ qlo,
                                                   u16* __restrict__ khi, u16* __restrict__ klo) {
  __shared__ u16 Ah[8192], Al[8192], Bh[8192], Bl[8192];  // 64 KiB
  const int tid = threadIdx.x;
  const int wave = tid >> 6, lane = tid & 63;
  const int wr = wave >> 1, wc = wave & 1;
  const int n0 = blockIdx.x * 128;  // W output channel (q then k)
  const int m0 = blockIdx.y * 128;  // x row (b*L + l)
  f32x4 acc[4][4] = {};
  for (int k0 = 0; k0 < kD; k0 += 64) {
    __syncthreads();
#pragma unroll
    for (int c2 = 0; c2 < 4; ++c2) {
      const int chunk = tid + c2 * 256;
      const int idx = chunk >> 3, cc = chunk & 7;
      const int lo = (((idx >> 4) * 8 + cc) * 16 + (idx & 15)) * 8;
      const size_t gw = (size_t)(n0 + idx) * kD + k0 + cc * 8;
      const size_t gx = (size_t)(m0 + idx) * kD + k0 + cc * 8;
      *reinterpret_cast<u16x8*>(&Ah[lo]) = *reinterpret_cast<const u16x8*>(wh + gw);
      *reinterpret_cast<u16x8*>(&Al[lo]) = *reinterpret_cast<const u16x8*>(wl + gw);
      *reinterpret_cast<u16x8*>(&Bh[lo]) = *reinterpret_cast<const u16x8*>(xh + gx);
      *reinterpret_cast<u16x8*>(&Bl[lo]) = *reinterpret_cast<const u16x8*>(xl + gx);
    }
    __syncthreads();
#pragma unroll
    for (int w = 0; w < 2; ++w) {
      const int kc = w * 4 + (lane >> 4);
      bf16x8 Afh[4], Afl[4], Bfh[4], Bfl[4];
#pragma unroll
      for (int i = 0; i < 4; ++i) {
        const int la = (((wr * 4 + i) * 8 + kc) * 16 + (lane & 15)) * 8;
        const int lb = (((wc * 4 + i) * 8 + kc) * 16 + (lane & 15)) * 8;
        Afh[i] = *reinterpret_cast<const bf16x8*>(&Ah[la]);
        Afl[i] = *reinterpret_cast<const bf16x8*>(&Al[la]);
        Bfh[i] = *reinterpret_cast<const bf16x8*>(&Bh[lb]);
        Bfl[i] = *reinterpret_cast<const bf16x8*>(&Bl[lb]);
      }
#pragma unroll
      for (int i = 0; i < 4; ++i)
#pragma unroll
        for (int j = 0; j < 4; ++j) {
          acc[i][j] = __builtin_amdgcn_mfma_f32_16x16x32_bf16(Afh[i], Bfh[j], acc[i][j], 0, 0, 0);
          acc[i][j] = __builtin_amdgcn_mfma_f32_16x16x32_bf16(Afh[i], Bfl[j], acc[i][j], 0, 0, 0);
          acc[i][j] = __builtin_amdgcn_mfma_f32_16x16x32_bf16(Afl[i], Bfh[j], acc[i][j], 0, 0, 0);
        }
    }
  }
  // epilogue: n -> (q/k, h, hd), m -> (b, l); lane holds 4 consecutive hd (rows of D)
  const int hglob = (n0 + wr * 64) >> 6;   // 0..31
  const bool isq = hglob < 16;
  const int hh = hglob & 15;
  u16* __restrict__ dh = isq ? qhi : khi;
  u16* __restrict__ dl = isq ? qlo : klo;
#pragma unroll
  for (int i = 0; i < 4; ++i) {
    const int hd0 = i * 16 + ((lane >> 4) << 2);
    const f32x4 b4 = *reinterpret_cast<const f32x4*>(bias + n0 + wr * 64 + hd0);
#pragma unroll
    for (int j = 0; j < 4; ++j) {
      const int m = m0 + wc * 64 + j * 16 + (lane & 15);
      const int bb = m >> 11, ll = m & (kL - 1);
      ushort4 vh, vl;
#pragma unroll
      for (int r = 0; r < 4; ++r) {
        const float v = acc[i][j][r] + b4[r];
        const u16 hu = f2bf(v);
        ((u16*)&vh)[r] = hu;
        ((u16*)&vl)[r] = f2bf(v - bf2f(hu));
      }
      const size_t o = (((size_t)bb * kH + hh) * kL + ll) * kHD + hd0;
      *reinterpret_cast<ushort4*>(dh + o) = vh;
      *reinterpret_cast<ushort4*>(dl + o) = vl;
    }
  }
}

// ---------------------------------------------------------------------------
// K2: softmax stats via MFMA (hi/lo split).
// ---------------------------------------------------------------------------
__global__ __launch_bounds__(256) void k_stats(const u16* __restrict__ qh, const u16* __restrict__ ql,
                                               const u16* __restrict__ kh, const u16* __restrict__ kl,
                                               float* __restrict__ mo, float* __restrict__ ilo) {
  __shared__ u16 Kh[4096];
  __shared__ u16 Kl[4096];
  const int tid = threadIdx.x;
  const int wave = tid >> 6, lane = tid & 63;
  const int qt = blockIdx.x;
  const int bh = blockIdx.y;
  const size_t base = (size_t)bh * kL * kHD;
  const int row0 = qt * 64 + wave * 16;
  const size_t qoff = base + (size_t)(row0 + (lane & 15)) * kHD + (lane >> 4) * 8;
  const bf16x8 aqh0 = *reinterpret_cast<const bf16x8*>(qh + qoff);
  const bf16x8 aqh1 = *reinterpret_cast<const bf16x8*>(qh + qoff + 32);
  const bf16x8 aql0 = *reinterpret_cast<const bf16x8*>(ql + qoff);
  const bf16x8 aql1 = *reinterpret_cast<const bf16x8*>(ql + qoff + 32);
  float m[4], l[4];
#pragma unroll
  for (int r = 0; r < 4; ++r) { m[r] = -INFINITY; l[r] = 0.f; }
  for (int kt = 0; kt < kL; kt += 64) {
    __syncthreads();
#pragma unroll
    for (int c = tid; c < 512; c += 256) {
      const int col = c >> 3, cc = c & 7;
      const size_t g = base + (size_t)(kt + col) * kHD + cc * 8;
      const int lo = ((((col >> 4) * 2 + (cc >> 2)) * 4 + (cc & 3)) * 16 + (col & 15)) * 8;
      *reinterpret_cast<u16x8*>(&Kh[lo]) = *reinterpret_cast<const u16x8*>(kh + g);
      *reinterpret_cast<u16x8*>(&Kl[lo]) = *reinterpret_cast<const u16x8*>(kl + g);
    }
    __syncthreads();
#pragma unroll
    for (int cs = 0; cs < 4; ++cs) {
      const int f0 = (((cs * 2 + 0) * 4 + (lane >> 4)) * 16 + (lane & 15)) * 8;
      const int f1 = (((cs * 2 + 1) * 4 + (lane >> 4)) * 16 + (lane & 15)) * 8;
      const bf16x8 bh0 = *reinterpret_cast<const bf16x8*>(&Kh[f0]);
      const bf16x8 bh1 = *reinterpret_cast<const bf16x8*>(&Kh[f1]);
      const bf16x8 bl0 = *reinterpret_cast<const bf16x8*>(&Kl[f0]);
      const bf16x8 bl1 = *reinterpret_cast<const bf16x8*>(&Kl[f1]);
      f32x4 s = {0.f, 0.f, 0.f, 0.f};
      s = __builtin_amdgcn_mfma_f32_16x16x32_bf16(aqh0, bh0, s, 0, 0, 0);
      s = __builtin_amdgcn_mfma_f32_16x16x32_bf16(aqh1, bh1, s, 0, 0, 0);
      s = __builtin_amdgcn_mfma_f32_16x16x32_bf16(aqh0, bl0, s, 0, 0, 0);
      s = __builtin_amdgcn_mfma_f32_16x16x32_bf16(aqh1, bl1, s, 0, 0, 0);
      s = __builtin_amdgcn_mfma_f32_16x16x32_bf16(aql0, bh0, s, 0, 0, 0);
      s = __builtin_amdgcn_mfma_f32_16x16x32_bf16(aql1, bh1, s, 0, 0, 0);
#pragma unroll
      for (int r = 0; r < 4; ++r) {
        const float sc = s[r] * kScale;
        const float nm = fmaxf(m[r], sc);
        l[r] = l[r] * __expf(m[r] - nm) + __expf(sc - nm);
        m[r] = nm;
      }
    }
  }
#pragma unroll
  for (int r = 0; r < 4; ++r) {
#pragma unroll
    for (int off = 1; off < 16; off <<= 1) {
      const float mo2 = __shfl_xor(m[r], off);
      const float lo2 = __shfl_xor(l[r], off);
      const float nm = fmaxf(m[r], mo2);
      l[r] = l[r] * __expf(m[r] - nm) + lo2 * __expf(mo2 - nm);
      m[r] = nm;
    }
  }
  if ((lane & 15) == 0) {
#pragma unroll
    for (int r = 0; r < 4; ++r) {
      const int row = row0 + (lane >> 4) * 4 + r;
      mo[(size_t)bh * kL + row] = m[r];
      ilo[(size_t)bh * kL + row] = 1.0f / l[r];
    }
  }
}

// ---------------------------------------------------------------------------
// K3: head-mean weights via MFMA.
// ---------------------------------------------------------------------------
__global__ __launch_bounds__(256) void k_attn(const u16* __restrict__ qh, const u16* __restrict__ ql,
                                              const u16* __restrict__ kh, const u16* __restrict__ kl,
                                              const float* __restrict__ ms, const float* __restrict__ ils,
                                              const float* __restrict__ td,
                                              float* __restrict__ attn, float* __restrict__ rowsum) {
  __shared__ u16 Kh[8192];
  __shared__ u16 Kl[8192];
  __shared__ float msS[16][64];
  __shared__ float ilS[16][64];
  const int tid = threadIdx.x;
  const int wave = tid >> 6, lane = tid & 63;
  const int kb = blockIdx.x;
  const int qb = blockIdx.y;
  const int b = blockIdx.z;
#pragma unroll
  for (int c = tid; c < 1024; c += 256) {
    const int h = c >> 6, r = c & 63;
    msS[h][r] = ms[((size_t)b * kH + h) * kL + qb * 64 + r];
    ilS[h][r] = ils[((size_t)b * kH + h) * kL + qb * 64 + r];
  }
  const int row0 = qb * 64 + wave * 16;
  float wacc[8][4] = {};
  for (int h = 0; h < kH; ++h) {
    const size_t base = ((size_t)b * kH + h) * kL * kHD;
    __syncthreads();
#pragma unroll
    for (int c = tid; c < 1024; c += 256) {
      const int col = c >> 3, cc = c & 7;
      const size_t g = base + (size_t)(kb * 128 + col) * kHD + cc * 8;
      const int lo = ((((col >> 4) * 2 + (cc >> 2)) * 4 + (cc & 3)) * 16 + (col & 15)) * 8;
      *reinterpret_cast<u16x8*>(&Kh[lo]) = *reinterpret_cast<const u16x8*>(kh + g);
      *reinterpret_cast<u16x8*>(&Kl[lo]) = *reinterpret_cast<const u16x8*>(kl + g);
    }
    __syncthreads();
    const size_t qoff = base + (size_t)(row0 + (lane & 15)) * kHD + (lane >> 4) * 8;
    const bf16x8 aqh0 = *reinterpret_cast<const bf16x8*>(qh + qoff);
    const bf16x8 aqh1 = *reinterpret_cast<const bf16x8*>(qh + qoff + 32);
    const bf16x8 aql0 = *reinterpret_cast<const bf16x8*>(ql + qoff);
    const bf16x8 aql1 = *reinterpret_cast<const bf16x8*>(ql + qoff + 32);
    const f32x4 mrow = *reinterpret_cast<const f32x4*>(&msS[h][wave * 16 + (lane >> 4) * 4]);
    const f32x4 irow = *reinterpret_cast<const f32x4*>(&ilS[h][wave * 16 + (lane >> 4) * 4]);
#pragma unroll
    for (int cs = 0; cs < 8; ++cs) {
      const int f0 = (((cs * 2 + 0) * 4 + (lane >> 4)) * 16 + (lane & 15)) * 8;
      const int f1 = (((cs * 2 + 1) * 4 + (lane >> 4)) * 16 + (lane & 15)) * 8;
      const bf16x8 bkh0 = *reinterpret_cast<const bf16x8*>(&Kh[f0]);
      const bf16x8 bkh1 = *reinterpret_cast<const bf16x8*>(&Kh[f1]);
      const bf16x8 bkl0 = *reinterpret_cast<const bf16x8*>(&Kl[f0]);
      const bf16x8 bkl1 = *reinterpret_cast<const bf16x8*>(&Kl[f1]);
      f32x4 s = {0.f, 0.f, 0.f, 0.f};
      s = __builtin_amdgcn_mfma_f32_16x16x32_bf16(aqh0, bkh0, s, 0, 0, 0);
      s = __builtin_amdgcn_mfma_f32_16x16x32_bf16(aqh1, bkh1, s, 0, 0, 0);
      s = __builtin_amdgcn_mfma_f32_16x16x32_bf16(aqh0, bkl0, s, 0, 0, 0);
      s = __builtin_amdgcn_mfma_f32_16x16x32_bf16(aqh1, bkl1, s, 0, 0, 0);
      s = __builtin_amdgcn_mfma_f32_16x16x32_bf16(aql0, bkh0, s, 0, 0, 0);
      s = __builtin_amdgcn_mfma_f32_16x16x32_bf16(aql1, bkh1, s, 0, 0, 0);
#pragma unroll
      for (int r = 0; r < 4; ++r)
        wacc[cs][r] += __expf(fmaf(s[r], kScale, -mrow[r])) * irow[r];
    }
  }
  const float invH = 1.0f / kH;
#pragma unroll
  for (int r = 0; r < 4; ++r) {
    const int row = row0 + (lane >> 4) * 4 + r;
    float rs = 0.f;
#pragma unroll
    for (int cs = 0; cs < 8; ++cs) {
      const int col = kb * 128 + cs * 16 + (lane & 15);
      const size_t idx = ((size_t)b * kL + row) * kL + col;
      const float o = wacc[cs][r] * invH * __expf(-kRecency * td[idx]);
      attn[idx] = o;
      rs += o;
    }
#pragma unroll
    for (int off = 1; off < 16; off <<= 1) rs += __shfl_xor(rs, off);
    if ((lane & 15) == 0) atomicAdd(&rowsum[(size_t)b * kL + row], rs);
  }
}

// ---------------------------------------------------------------------------
// K4a: row renormalization; also emits normalized weights as bf16 (hi).
// ---------------------------------------------------------------------------
__global__ __launch_bounds__(256) void k_norm(float* __restrict__ attn,
                                              const float* __restrict__ rowsum,
                                              u16* __restrict__ abf) {
  const int row = blockIdx.x;
  const float inv = 1.0f / (rowsum[row] + kEps);
  float* p = attn + (size_t)row * kL;
  u16* q = abf + (size_t)row * kL;
  const int i0 = threadIdx.x * 8;
  float4 a = *reinterpret_cast<float4*>(p + i0);
  float4 b = *reinterpret_cast<float4*>(p + i0 + 4);
  a.x *= inv; a.y *= inv; a.z *= inv; a.w *= inv;
  b.x *= inv; b.y *= inv; b.z *= inv; b.w *= inv;
  *reinterpret_cast<float4*>(p + i0) = a;
  *reinterpret_cast<float4*>(p + i0 + 4) = b;
  u16x8 h;
  h[0] = f2bf(a.x); h[1] = f2bf(a.y); h[2] = f2bf(a.z); h[3] = f2bf(a.w);
  h[4] = f2bf(b.x); h[5] = f2bf(b.y); h[6] = f2bf(b.z); h[7] = f2bf(b.w);
  *reinterpret_cast<u16x8*>(q + i0) = h;
}

// ---------------------------------------------------------------------------
// K4b: LDS-tiled transpose x -> xT [b][d][l] bf16 hi/lo.
// ---------------------------------------------------------------------------
__global__ __launch_bounds__(256) void k_cvt_xT(const float* __restrict__ x,
                                                u16* __restrict__ xth, u16* __restrict__ xtl) {
  __shared__ u16 Th[64][72];
  __shared__ u16 Tl[64][72];
  const int tid = threadIdx.x;
  const int l0 = blockIdx.x * 64, d0 = blockIdx.y * 64, b = blockIdx.z;
#pragma unroll
  for (int rep = 0; rep < 4; ++rep) {
    const int lr = (tid >> 4) + rep * 16;
    const int dc = (tid & 15) * 4;
    const float4 v = *reinterpret_cast<const float4*>(x + ((size_t)b * kL + l0 + lr) * kD + d0 + dc);
    const float vv[4] = {v.x, v.y, v.z, v.w};
#pragma unroll
    for (int c = 0; c < 4; ++c) {
      const u16 hu = f2bf(vv[c]);
      Th[dc + c][lr] = hu;
      Tl[dc + c][lr] = f2bf(vv[c] - bf2f(hu));
    }
  }
  __syncthreads();
#pragma unroll
  for (int rep = 0; rep < 2; ++rep) {
    const int chunk = tid + rep * 256;
    const int dd = chunk >> 3, part = chunk & 7;
    const size_t o = ((size_t)b * kD + d0 + dd) * kL + l0 + part * 8;
    *reinterpret_cast<u16x8*>(xth + o) = *reinterpret_cast<const u16x8*>(&Th[dd][part * 8]);
    *reinterpret_cast<u16x8*>(xtl + o) = *reinterpret_cast<const u16x8*>(&Tl[dd][part * 8]);
  }
}

// ---------------------------------------------------------------------------
// K5: output GEMM via MFMA: out[b,m,n] = sum_k attn_bf[b,m,k] * x[b,k,n].
// A = attn (hi only), B = xT hi/lo, 2-term. 128x128 tile, K_STEP=64.
// ---------------------------------------------------------------------------
__global__ __launch_bounds__(256, 2) void k_out(const u16* __restrict__ abf,
                                                const u16* __restrict__ xth, const u16* __restrict__ xtl,
                                                float* __restrict__ out) {
  __shared__ u16 Ah[8192], Bh[8192], Bl[8192];  // 48 KiB
  const int tid = threadIdx.x;
  const int wave = tid >> 6, lane = tid & 63;
  const int wr = wave >> 1, wc = wave & 1;
  const int m0 = blockIdx.x * 128;  // attn row
  const int n0 = blockIdx.y * 128;  // d col
  const int b = blockIdx.z;
  f32x4 acc[4][4] = {};
  for (int k0 = 0; k0 < kL; k0 += 64) {
    __syncthreads();
#pragma unroll
    for (int c2 = 0; c2 < 4; ++c2) {
      const int chunk = tid + c2 * 256;
      const int idx = chunk >> 3, cc = chunk & 7;
      const int lo = (((idx >> 4) * 8 + cc) * 16 + (idx & 15)) * 8;
      const size_t ga = ((size_t)b * kL + m0 + idx) * kL + k0 + cc * 8;
      const size_t gb = ((size_t)b * kD + n0 + idx) * kL + k0 + cc * 8;
      *reinterpret_cast<u16x8*>(&Ah[lo]) = *reinterpret_cast<const u16x8*>(abf + ga);
      *reinterpret_cast<u16x8*>(&Bh[lo]) = *reinterpret_cast<const u16x8*>(xth + gb);
      *reinterpret_cast<u16x8*>(&Bl[lo]) = *reinterpret_cast<const u16x8*>(xtl + gb);
    }
    __syncthreads();
#pragma unroll
    for (int w = 0; w < 2; ++w) {
      const int kc = w * 4 + (lane >> 4);
      bf16x8 Afh[4], Bfh[4], Bfl[4];
#pragma unroll
      for (int i = 0; i < 4; ++i) {
        const int la = (((wr * 4 + i) * 8 + kc) * 16 + (lane & 15)) * 8;
        const int lb = (((wc * 4 + i) * 8 + kc) * 16 + (lane & 15)) * 8;
        Afh[i] = *reinterpret_cast<const bf16x8*>(&Ah[la]);
        Bfh[i] = *reinterpret_cast<const bf16x8*>(&Bh[lb]);
        Bfl[i] = *reinterpret_cast<const bf16x8*>(&Bl[lb]);
      }
#pragma unroll
      for (int i = 0; i < 4; ++i)
#pragma unroll
        for (int j = 0; j < 4; ++j) {
          acc[i][j] = __builtin_amdgcn_mfma_f32_16x16x32_bf16(Afh[i], Bfh[j], acc[i][j], 0, 0, 0);
          acc[i][j] = __builtin_amdgcn_mfma_f32_16x16x32_bf16(Afh[i], Bfl[j], acc[i][j], 0, 0, 0);
        }
    }
  }
#pragma unroll
  for (int i = 0; i < 4; ++i) {
    const int row = m0 + wr * 64 + i * 16 + ((lane >> 4) << 2);
#pragma unroll
    for (int j = 0; j < 4; ++j) {
      const int col = n0 + wc * 64 + j * 16 + (lane & 15);
#pragma unroll
      for (int r = 0; r < 4; ++r)
        out[((size_t)b * kL + row + r) * kD + col] = acc[i][j][r];
    }
  }
}

extern "C" void kernel_launch(void* const* d_in, const int* in_sizes, int n_in,
                              void* d_out, int out_size, void* d_ws, size_t ws_size,
                              hipStream_t stream) {
  (void)in_sizes; (void)n_in; (void)out_size; (void)ws_size;
  const float* x = (const float*)d_in[0];
  const float* td = (const float*)d_in[1];
  const float* w = (const float*)d_in[2];
  const float* bias = (const float*)d_in[3];
  float* out = (float*)d_out;                        // [B,L,D]
  float* attn = out + (size_t)kB * kL * kD;          // [B,L,L]

  u16* base = (u16*)d_ws;
  u16* qhi = base;
  u16* qlo = base + kN4;
  u16* khi = base + 2 * kN4;
  u16* klo = base + 3 * kN4;
  u16* xah = base + 4 * kN4;   // x bf16 straight; later reused as attn_bf
  u16* xal = base + 5 * kN4;
  u16* attn_bf = xah;          // spans xah+xal (8.39M u16)
  u16* xth = qhi;              // xT aliases q (q dead after k_attn)
  u16* xtl = qlo;
  u16* whi = base + 6 * kN4;
  u16* wlo = whi + 2097152;
  float* fb = (float*)(wlo + 2097152);
  float* mb = fb;
  float* ilb = fb + 65536;
  float* rsb = fb + 131072;

  hipLaunchKernelGGL(k_cvt_xw, dim3(6144), dim3(256), 0, stream, x, w, xah, xal, whi, wlo);
  hipLaunchKernelGGL(k_qkproj, dim3(16, 32), dim3(256), 0, stream, xah, xal, whi, wlo, bias,
                     qhi, qlo, khi, klo);
  hipLaunchKernelGGL(k_stats, dim3(32, 32), dim3(256), 0, stream, qhi, qlo, khi, klo, mb, ilb);
  hipMemsetAsync(rsb, 0, (size_t)kB * kL * sizeof(float), stream);
  hipLaunchKernelGGL(k_attn, dim3(16, 32, 2), dim3(256), 0, stream, qhi, qlo, khi, klo, mb, ilb,
                     td, attn, rsb);
  hipLaunchKernelGGL(k_norm, dim3(kB * kL), dim3(256), 0, stream, attn, rsb, attn_bf);
  hipLaunchKernelGGL(k_cvt_xT, dim3(32, 16, 2), dim3(256), 0, stream, x, xth, xtl);
  hipLaunchKernelGGL(k_out, dim3(16, 8, 2), dim3(256), 0, stream, attn_bf, xth, xtl, out);
}

// Round 5
// 407.085 us; speedup vs baseline: 3.0424x; 1.2456x over previous
//
#include <hip/hip_runtime.h>
#include <hip/hip_bf16.h>
#include <math.h>

namespace {
constexpr int kB = 2;
constexpr int kL = 2048;
constexpr int kD = 1024;
constexpr int kH = 16;
constexpr int kHD = 64;
// softmax scale (HD^-0.5 = 0.125) * log2(e): fold into q so scores live in exp2 domain
constexpr float kQScale = 0.125f * 1.44269504088896340736f;
constexpr float kDecay2 = -0.1f * 1.44269504088896340736f;  // temporal decay in exp2 domain
constexpr float kEps = 1e-8f;
constexpr size_t kN4 = 4194304;  // B*L*D = B*H*L*HD elements
}  // namespace

typedef _Float16 f16;
typedef f16 f16x4 __attribute__((ext_vector_type(4)));
typedef f16 f16x8 __attribute__((ext_vector_type(8)));
typedef float f32x4 __attribute__((ext_vector_type(4)));

// ---------------------------------------------------------------------------
// K0: convert x -> fp16 hi; W[0:2048] -> fp16 hi/lo.
// ---------------------------------------------------------------------------
__global__ __launch_bounds__(256) void k_cvt_xw(const float* __restrict__ x,
                                                const float* __restrict__ w,
                                                f16* __restrict__ xh,
                                                f16* __restrict__ wh, f16* __restrict__ wl) {
  const size_t id = (size_t)blockIdx.x * 256 + threadIdx.x;  // float4 index
  if (id < 1048576) {
    const float4 v = reinterpret_cast<const float4*>(x)[id];
    const float vv[4] = {v.x, v.y, v.z, v.w};
    f16x4 h;
#pragma unroll
    for (int c = 0; c < 4; ++c) h[c] = (f16)vv[c];
    *reinterpret_cast<f16x4*>(xh + id * 4) = h;
  } else {
    const size_t id2 = id - 1048576;
    const float4 v = reinterpret_cast<const float4*>(w)[id2];
    const float vv[4] = {v.x, v.y, v.z, v.w};
    f16x4 h, l;
#pragma unroll
    for (int c = 0; c < 4; ++c) {
      h[c] = (f16)vv[c];
      l[c] = (f16)(vv[c] - (float)h[c]);
    }
    *reinterpret_cast<f16x4*>(wh + id2 * 4) = h;
    *reinterpret_cast<f16x4*>(wl + id2 * 4) = l;
  }
}

// ---------------------------------------------------------------------------
// K1: q/k projection via MFMA fp16 2-term (Wh*xh + Wl*xh).
// 128(n) x 128(m) tile, K_STEP=64, padded frag-order LDS (272B rows).
// q written scaled by kQScale as fp16 hi/lo; k written fp16 hi only.
// ---------------------------------------------------------------------------
__global__ __launch_bounds__(256, 2) void k_qkproj(const f16* __restrict__ xh,
                                                   const f16* __restrict__ wh, const f16* __restrict__ wl,
                                                   const float* __restrict__ bias,
                                                   f16* __restrict__ qhi, f16* __restrict__ qlo,
                                                   f16* __restrict__ khi) {
  __shared__ f16 Ah[8704], Al[8704], Bh[8704];  // 64 rows x 136 f16 (272B, padded)
  const int tid = threadIdx.x;
  const int wave = tid >> 6, lane = tid & 63;
  const int wr = wave >> 1, wc = wave & 1;
  const int n0 = blockIdx.x * 128;  // W output channel
  const int m0 = blockIdx.y * 128;  // x row (b*L + l)
  f32x4 acc[4][4] = {};
  for (int k0 = 0; k0 < kD; k0 += 64) {
    __syncthreads();
#pragma unroll
    for (int c2 = 0; c2 < 4; ++c2) {
      const int chunk = tid + c2 * 256;
      const int idx = chunk >> 3, cc = chunk & 7;
      const int lo = ((idx >> 4) * 8 + cc) * 136 + (idx & 15) * 8;
      const size_t gw = (size_t)(n0 + idx) * kD + k0 + cc * 8;
      const size_t gx = (size_t)(m0 + idx) * kD + k0 + cc * 8;
      *reinterpret_cast<f16x8*>(&Ah[lo]) = *reinterpret_cast<const f16x8*>(wh + gw);
      *reinterpret_cast<f16x8*>(&Al[lo]) = *reinterpret_cast<const f16x8*>(wl + gw);
      *reinterpret_cast<f16x8*>(&Bh[lo]) = *reinterpret_cast<const f16x8*>(xh + gx);
    }
    __syncthreads();
#pragma unroll
    for (int z = 0; z < 2; ++z) {
      const int kc = z * 4 + (lane >> 4);
      f16x8 Afh[4], Afl[4], Bfh[4];
#pragma unroll
      for (int i = 0; i < 4; ++i) {
        const int la = ((wr * 4 + i) * 8 + kc) * 136 + (lane & 15) * 8;
        const int lb = ((wc * 4 + i) * 8 + kc) * 136 + (lane & 15) * 8;
        Afh[i] = *reinterpret_cast<const f16x8*>(&Ah[la]);
        Afl[i] = *reinterpret_cast<const f16x8*>(&Al[la]);
        Bfh[i] = *reinterpret_cast<const f16x8*>(&Bh[lb]);
      }
#pragma unroll
      for (int i = 0; i < 4; ++i)
#pragma unroll
        for (int j = 0; j < 4; ++j) {
          acc[i][j] = __builtin_amdgcn_mfma_f32_16x16x32_f16(Afh[i], Bfh[j], acc[i][j], 0, 0, 0);
          acc[i][j] = __builtin_amdgcn_mfma_f32_16x16x32_f16(Afl[i], Bfh[j], acc[i][j], 0, 0, 0);
        }
    }
  }
  const int hglob = (n0 + wr * 64) >> 6;  // 0..31
  const bool isq = hglob < 16;
  const int hh = hglob & 15;
#pragma unroll
  for (int i = 0; i < 4; ++i) {
    const int hd0 = i * 16 + ((lane >> 4) << 2);
    const f32x4 b4 = *reinterpret_cast<const f32x4*>(bias + n0 + wr * 64 + hd0);
#pragma unroll
    for (int j = 0; j < 4; ++j) {
      const int m = m0 + wc * 64 + j * 16 + (lane & 15);
      const int bb = m >> 11, ll = m & (kL - 1);
      const size_t o = (((size_t)bb * kH + hh) * kL + ll) * kHD + hd0;
      if (isq) {
        f16x4 vh, vl;
#pragma unroll
        for (int r = 0; r < 4; ++r) {
          const float v = (acc[i][j][r] + b4[r]) * kQScale;
          vh[r] = (f16)v;
          vl[r] = (f16)(v - (float)vh[r]);
        }
        *reinterpret_cast<f16x4*>(qhi + o) = vh;
        *reinterpret_cast<f16x4*>(qlo + o) = vl;
      } else {
        f16x4 vh;
#pragma unroll
        for (int r = 0; r < 4; ++r) vh[r] = (f16)(acc[i][j][r] + b4[r]);
        *reinterpret_cast<f16x4*>(khi + o) = vh;
      }
    }
  }
}

// ---------------------------------------------------------------------------
// K2: softmax denominators. No LDS, no barriers: K-frags read direct from
// global (coalesced; L1/L2-resident). l = sum exp2(s); nl = -log2(l) - 4.
// ---------------------------------------------------------------------------
__global__ __launch_bounds__(256) void k_stats(const f16* __restrict__ qh, const f16* __restrict__ ql,
                                               const f16* __restrict__ kh,
                                               float* __restrict__ nlo) {
  const int tid = threadIdx.x;
  const int wave = tid >> 6, lane = tid & 63;
  const int qt = blockIdx.x;   // 0..31
  const int bh = blockIdx.y;   // 0..31
  const size_t base = (size_t)bh * kL * kHD;
  const int row0 = qt * 64 + wave * 16;
  const size_t qoff = base + (size_t)(row0 + (lane & 15)) * kHD + (lane >> 4) * 8;
  const f16x8 aqh0 = *reinterpret_cast<const f16x8*>(qh + qoff);
  const f16x8 aqh1 = *reinterpret_cast<const f16x8*>(qh + qoff + 32);
  const f16x8 aql0 = *reinterpret_cast<const f16x8*>(ql + qoff);
  const f16x8 aql1 = *reinterpret_cast<const f16x8*>(ql + qoff + 32);
  const f16* kp = kh + base + ((lane & 15) << 6) + ((lane >> 4) << 3);
  float l[4] = {0.f, 0.f, 0.f, 0.f};
#pragma unroll 8
  for (int kt = 0; kt < kL; kt += 16) {
    const f16* p = kp + (size_t)kt * kHD;
    const f16x8 b0 = *reinterpret_cast<const f16x8*>(p);
    const f16x8 b1 = *reinterpret_cast<const f16x8*>(p + 32);
    f32x4 s = {0.f, 0.f, 0.f, 0.f};
    s = __builtin_amdgcn_mfma_f32_16x16x32_f16(aqh0, b0, s, 0, 0, 0);
    s = __builtin_amdgcn_mfma_f32_16x16x32_f16(aql0, b0, s, 0, 0, 0);
    s = __builtin_amdgcn_mfma_f32_16x16x32_f16(aqh1, b1, s, 0, 0, 0);
    s = __builtin_amdgcn_mfma_f32_16x16x32_f16(aql1, b1, s, 0, 0, 0);
#pragma unroll
    for (int r = 0; r < 4; ++r) l[r] += exp2f(s[r]);
  }
#pragma unroll
  for (int r = 0; r < 4; ++r) {
#pragma unroll
    for (int off = 1; off < 16; off <<= 1) l[r] += __shfl_xor(l[r], off);
  }
  if ((lane & 15) == 0) {
#pragma unroll
    for (int r = 0; r < 4; ++r)
      nlo[(size_t)bh * kL + row0 + (lane >> 4) * 4 + r] = -log2f(l[r]) - 4.0f;
  }
}

// ---------------------------------------------------------------------------
// K3: head-mean weights. Padded frag-order LDS for K-hi; per element:
// w += exp2(s + nl[row]).  Epilogue applies decay, writes attn, rowsum.
// ---------------------------------------------------------------------------
__global__ __launch_bounds__(256) void k_attn(const f16* __restrict__ qh, const f16* __restrict__ ql,
                                              const f16* __restrict__ kh,
                                              const float* __restrict__ nl,
                                              const float* __restrict__ td,
                                              float* __restrict__ attn, float* __restrict__ rowsum) {
  __shared__ f16 Kh[8704];       // 64 rows x 136 f16 (padded)
  __shared__ float nlS[16][64];
  const int tid = threadIdx.x;
  const int wave = tid >> 6, lane = tid & 63;
  const int kb = blockIdx.x;  // 0..15 (128 k-cols)
  const int qb = blockIdx.y;  // 0..31 (64 q-rows)
  const int b = blockIdx.z;
#pragma unroll
  for (int c = tid; c < 1024; c += 256)
    nlS[c >> 6][c & 63] = nl[((size_t)b * kH + (c >> 6)) * kL + qb * 64 + (c & 63)];
  const int row0 = qb * 64 + wave * 16;
  float wacc[8][4] = {};
  for (int h = 0; h < kH; ++h) {
    const size_t base = ((size_t)b * kH + h) * kL * kHD;
    const size_t qoff = base + (size_t)(row0 + (lane & 15)) * kHD + (lane >> 4) * 8;
    const f16x8 aqh0 = *reinterpret_cast<const f16x8*>(qh + qoff);
    const f16x8 aqh1 = *reinterpret_cast<const f16x8*>(qh + qoff + 32);
    const f16x8 aql0 = *reinterpret_cast<const f16x8*>(ql + qoff);
    const f16x8 aql1 = *reinterpret_cast<const f16x8*>(ql + qoff + 32);
    __syncthreads();
#pragma unroll
    for (int c2 = 0; c2 < 4; ++c2) {
      const int chunk = tid + c2 * 256;
      const int col = chunk >> 3, cc = chunk & 7;
      const int lo = ((col >> 4) * 8 + cc) * 136 + (col & 15) * 8;
      *reinterpret_cast<f16x8*>(&Kh[lo]) =
          *reinterpret_cast<const f16x8*>(kh + base + (size_t)(kb * 128 + col) * kHD + cc * 8);
    }
    __syncthreads();
    const f32x4 nlr = *reinterpret_cast<const f32x4*>(&nlS[h][wave * 16 + (lane >> 4) * 4]);
#pragma unroll
    for (int cs = 0; cs < 8; ++cs) {
      const int r0 = (cs * 8 + (lane >> 4)) * 136 + (lane & 15) * 8;
      const f16x8 b0 = *reinterpret_cast<const f16x8*>(&Kh[r0]);
      const f16x8 b1 = *reinterpret_cast<const f16x8*>(&Kh[r0 + 4 * 136]);
      f32x4 s = {0.f, 0.f, 0.f, 0.f};
      s = __builtin_amdgcn_mfma_f32_16x16x32_f16(aqh0, b0, s, 0, 0, 0);
      s = __builtin_amdgcn_mfma_f32_16x16x32_f16(aql0, b0, s, 0, 0, 0);
      s = __builtin_amdgcn_mfma_f32_16x16x32_f16(aqh1, b1, s, 0, 0, 0);
      s = __builtin_amdgcn_mfma_f32_16x16x32_f16(aql1, b1, s, 0, 0, 0);
#pragma unroll
      for (int r = 0; r < 4; ++r) wacc[cs][r] += exp2f(s[r] + nlr[r]);
    }
  }
#pragma unroll
  for (int r = 0; r < 4; ++r) {
    const int row = row0 + (lane >> 4) * 4 + r;
    float rs = 0.f;
#pragma unroll
    for (int cs = 0; cs < 8; ++cs) {
      const int col = kb * 128 + cs * 16 + (lane & 15);
      const size_t idx = ((size_t)b * kL + row) * kL + col;
      const float o = wacc[cs][r] * exp2f(kDecay2 * td[idx]);
      attn[idx] = o;
      rs += o;
    }
#pragma unroll
    for (int off = 1; off < 16; off <<= 1) rs += __shfl_xor(rs, off);
    if ((lane & 15) == 0) atomicAdd(&rowsum[(size_t)b * kL + row], rs);
  }
}

// ---------------------------------------------------------------------------
// K4a: row renormalization; also emits normalized weights as fp16.
// ---------------------------------------------------------------------------
__global__ __launch_bounds__(256) void k_norm(float* __restrict__ attn,
                                              const float* __restrict__ rowsum,
                                              f16* __restrict__ abf) {
  const int row = blockIdx.x;
  const float inv = 1.0f / (rowsum[row] + kEps);
  float* p = attn + (size_t)row * kL;
  f16* q = abf + (size_t)row * kL;
  const int i0 = threadIdx.x * 8;
  float4 a = *reinterpret_cast<float4*>(p + i0);
  float4 b = *reinterpret_cast<float4*>(p + i0 + 4);
  a.x *= inv; a.y *= inv; a.z *= inv; a.w *= inv;
  b.x *= inv; b.y *= inv; b.z *= inv; b.w *= inv;
  *reinterpret_cast<float4*>(p + i0) = a;
  *reinterpret_cast<float4*>(p + i0 + 4) = b;
  f16x8 h;
  h[0] = (f16)a.x; h[1] = (f16)a.y; h[2] = (f16)a.z; h[3] = (f16)a.w;
  h[4] = (f16)b.x; h[5] = (f16)b.y; h[6] = (f16)b.z; h[7] = (f16)b.w;
  *reinterpret_cast<f16x8*>(q + i0) = h;
}

// ---------------------------------------------------------------------------
// K4b: LDS-tiled transpose x -> xT [b][d][l] fp16 hi/lo.
// ---------------------------------------------------------------------------
__global__ __launch_bounds__(256) void k_cvt_xT(const float* __restrict__ x,
                                                f16* __restrict__ xth, f16* __restrict__ xtl) {
  __shared__ f16 Th[64][72];
  __shared__ f16 Tl[64][72];
  const int tid = threadIdx.x;
  const int l0 = blockIdx.x * 64, d0 = blockIdx.y * 64, b = blockIdx.z;
#pragma unroll
  for (int rep = 0; rep < 4; ++rep) {
    const int lr = (tid >> 4) + rep * 16;
    const int dc = (tid & 15) * 4;
    const float4 v = *reinterpret_cast<const float4*>(x + ((size_t)b * kL + l0 + lr) * kD + d0 + dc);
    const float vv[4] = {v.x, v.y, v.z, v.w};
#pragma unroll
    for (int c = 0; c < 4; ++c) {
      const f16 hu = (f16)vv[c];
      Th[dc + c][lr] = hu;
      Tl[dc + c][lr] = (f16)(vv[c] - (float)hu);
    }
  }
  __syncthreads();
#pragma unroll
  for (int rep = 0; rep < 2; ++rep) {
    const int chunk = tid + rep * 256;
    const int dd = chunk >> 3, part = chunk & 7;
    const size_t o = ((size_t)b * kD + d0 + dd) * kL + l0 + part * 8;
    *reinterpret_cast<f16x8*>(xth + o) = *reinterpret_cast<const f16x8*>(&Th[dd][part * 8]);
    *reinterpret_cast<f16x8*>(xtl + o) = *reinterpret_cast<const f16x8*>(&Tl[dd][part * 8]);
  }
}

// ---------------------------------------------------------------------------
// K5: output GEMM: out = attn_f16 @ x (xT hi/lo, 2-term). Padded frag LDS.
// ---------------------------------------------------------------------------
__global__ __launch_bounds__(256, 2) void k_out(const f16* __restrict__ abf,
                                                const f16* __restrict__ xth, const f16* __restrict__ xtl,
                                                float* __restrict__ out) {
  __shared__ f16 Ah[8704], Bh[8704], Bl[8704];
  const int tid = threadIdx.x;
  const int wave = tid >> 6, lane = tid & 63;
  const int wr = wave >> 1, wc = wave & 1;
  const int m0 = blockIdx.x * 128;  // attn row
  const int n0 = blockIdx.y * 128;  // d col
  const int b = blockIdx.z;
  f32x4 acc[4][4] = {};
  for (int k0 = 0; k0 < kL; k0 += 64) {
    __syncthreads();
#pragma unroll
    for (int c2 = 0; c2 < 4; ++c2) {
      const int chunk = tid + c2 * 256;
      const int idx = chunk >> 3, cc = chunk & 7;
      const int lo = ((idx >> 4) * 8 + cc) * 136 + (idx & 15) * 8;
      const size_t ga = ((size_t)b * kL + m0 + idx) * kL + k0 + cc * 8;
      const size_t gb = ((size_t)b * kD + n0 + idx) * kL + k0 + cc * 8;
      *reinterpret_cast<f16x8*>(&Ah[lo]) = *reinterpret_cast<const f16x8*>(abf + ga);
      *reinterpret_cast<f16x8*>(&Bh[lo]) = *reinterpret_cast<const f16x8*>(xth + gb);
      *reinterpret_cast<f16x8*>(&Bl[lo]) = *reinterpret_cast<const f16x8*>(xtl + gb);
    }
    __syncthreads();
#pragma unroll
    for (int z = 0; z < 2; ++z) {
      const int kc = z * 4 + (lane >> 4);
      f16x8 Afh[4], Bfh[4], Bfl[4];
#pragma unroll
      for (int i = 0; i < 4; ++i) {
        const int la = ((wr * 4 + i) * 8 + kc) * 136 + (lane & 15) * 8;
        const int lb = ((wc * 4 + i) * 8 + kc) * 136 + (lane & 15) * 8;
        Afh[i] = *reinterpret_cast<const f16x8*>(&Ah[la]);
        Bfh[i] = *reinterpret_cast<const f16x8*>(&Bh[lb]);
        Bfl[i] = *reinterpret_cast<const f16x8*>(&Bl[lb]);
      }
#pragma unroll
      for (int i = 0; i < 4; ++i)
#pragma unroll
        for (int j = 0; j < 4; ++j) {
          acc[i][j] = __builtin_amdgcn_mfma_f32_16x16x32_f16(Afh[i], Bfh[j], acc[i][j], 0, 0, 0);
          acc[i][j] = __builtin_amdgcn_mfma_f32_16x16x32_f16(Afh[i], Bfl[j], acc[i][j], 0, 0, 0);
        }
    }
  }
#pragma unroll
  for (int i = 0; i < 4; ++i) {
    const int row = m0 + wr * 64 + i * 16 + ((lane >> 4) << 2);
#pragma unroll
    for (int j = 0; j < 4; ++j) {
      const int col = n0 + wc * 64 + j * 16 + (lane & 15);
#pragma unroll
      for (int r = 0; r < 4; ++r)
        out[((size_t)b * kL + row + r) * kD + col] = acc[i][j][r];
    }
  }
}

extern "C" void kernel_launch(void* const* d_in, const int* in_sizes, int n_in,
                              void* d_out, int out_size, void* d_ws, size_t ws_size,
                              hipStream_t stream) {
  (void)in_sizes; (void)n_in; (void)out_size; (void)ws_size;
  const float* x = (const float*)d_in[0];
  const float* td = (const float*)d_in[1];
  const float* w = (const float*)d_in[2];
  const float* bias = (const float*)d_in[3];
  float* out = (float*)d_out;                        // [B,L,D]
  float* attn = out + (size_t)kB * kL * kD;          // [B,L,L]

  f16* base = (f16*)d_ws;
  f16* qh = base;                  // kN4
  f16* ql = base + kN4;            // kN4
  f16* kh = base + 2 * kN4;        // kN4
  f16* xh = base + 3 * kN4;        // kN4 (x fp16 hi; dead after k_qkproj)
  f16* wh = base + 4 * kN4;        // 2.10M
  f16* wl = wh + 2097152;          // 2.10M
  f16* attn_f16 = xh;              // aliases xh+wh+wl: 8.39M f16 (dead by k_norm time)
  f16* xth = qh;                   // xT aliases q (q dead after k_attn)
  f16* xtl = ql;
  float* fb = (float*)(wl + 2097152);
  float* nl = fb;                  // B*H*L = 65536
  float* rsb = fb + 65536;         // B*L = 4096

  hipLaunchKernelGGL(k_cvt_xw, dim3(6144), dim3(256), 0, stream, x, w, xh, wh, wl);
  hipLaunchKernelGGL(k_qkproj, dim3(16, 32), dim3(256), 0, stream, xh, wh, wl, bias, qh, ql, kh);
  hipLaunchKernelGGL(k_stats, dim3(32, 32), dim3(256), 0, stream, qh, ql, kh, nl);
  hipMemsetAsync(rsb, 0, (size_t)kB * kL * sizeof(float), stream);
  hipLaunchKernelGGL(k_attn, dim3(16, 32, 2), dim3(256), 0, stream, qh, ql, kh, nl, td, attn, rsb);
  hipLaunchKernelGGL(k_norm, dim3(kB * kL), dim3(256), 0, stream, attn, rsb, attn_f16);
  hipLaunchKernelGGL(k_cvt_xT, dim3(32, 16, 2), dim3(256), 0, stream, x, xth, xtl);
  hipLaunchKernelGGL(k_out, dim3(16, 8, 2), dim3(256), 0, stream, attn_f16, xth, xtl, out);
}